// Round 1
// baseline (4777.105 us; speedup 1.0000x reference)
//
#include <hip/hip_runtime.h>
#include <hip/hip_bf16.h>
#include <math.h>

#define L_SEQ   2048
#define BATCH   2
#define DMODEL  2048
#define DINNER  4096
#define DSTATE  16
#define DTRANK  128
#define NTOK    (L_SEQ * BATCH)   // 4096

// ---------------------------------------------------------------------------
// Generic fp32 GEMM:  C[m][n] = sum_k A[m*lda + k] * Bt[n*ldb + k]
// A: row-major MxK (lda >= K).  Bt: row-major NxK (ldb >= K)  (i.e. B^T).
// Tile 128x128, BK=16, 256 threads, 8x8 per thread.
// MODE 0: split store: m<4096 -> C0[n*4096+m] (x), else C1[n*4096+m-4096] (z)
// MODE 1: plain store C0[n*ldc + m]
// MODE 2: softplus(v + bias[m]) -> C0[n*ldc + m]
// MODE 3: plain store C0[n*ldc + m]   (output GEMM)
// N must be a multiple of 128 (true for all call sites: N=4096).
// K must be a multiple of 16 (2048/4096/128: ok). M may be ragged (160).
// ---------------------------------------------------------------------------
template <int MODE>
__global__ __launch_bounds__(256)
void gemm_tn(const float* __restrict__ A, const float* __restrict__ Bt,
             float* __restrict__ C0, float* __restrict__ C1,
             const float* __restrict__ bias,
             int M, int N, int K, int lda, int ldb, int ldc)
{
    __shared__ __align__(16) float As[16][128];
    __shared__ __align__(16) float Bs[16][128];

    const int m0 = blockIdx.y * 128;
    const int n0 = blockIdx.x * 128;
    const int t  = threadIdx.x;
    const int r    = t >> 1;          // 0..127: row of the tile this thread stages
    const int koff = (t & 1) * 8;     // first or second 8 k's
    const int tm0  = (t >> 4) * 8;    // this thread's 8 output rows
    const int tn0  = (t & 15) * 8;    // this thread's 8 output cols

    float acc[8][8];
#pragma unroll
    for (int i = 0; i < 8; ++i)
#pragma unroll
        for (int j = 0; j < 8; ++j) acc[i][j] = 0.f;

    for (int k0 = 0; k0 < K; k0 += 16) {
        // stage A tile (guarded on M edge)
        {
            const int gm = m0 + r;
            float4 a0 = {0, 0, 0, 0}, a1 = {0, 0, 0, 0};
            if (gm < M) {
                const float* p = A + (size_t)gm * lda + k0 + koff;
                a0 = *(const float4*)p;
                a1 = *(const float4*)(p + 4);
            }
            As[koff + 0][r] = a0.x; As[koff + 1][r] = a0.y;
            As[koff + 2][r] = a0.z; As[koff + 3][r] = a0.w;
            As[koff + 4][r] = a1.x; As[koff + 5][r] = a1.y;
            As[koff + 6][r] = a1.z; As[koff + 7][r] = a1.w;
        }
        // stage B tile (N always multiple of 128 -> no guard)
        {
            const int gn = n0 + r;
            const float* p = Bt + (size_t)gn * ldb + k0 + koff;
            float4 b0 = *(const float4*)p;
            float4 b1 = *(const float4*)(p + 4);
            Bs[koff + 0][r] = b0.x; Bs[koff + 1][r] = b0.y;
            Bs[koff + 2][r] = b0.z; Bs[koff + 3][r] = b0.w;
            Bs[koff + 4][r] = b1.x; Bs[koff + 5][r] = b1.y;
            Bs[koff + 6][r] = b1.z; Bs[koff + 7][r] = b1.w;
        }
        __syncthreads();

#pragma unroll
        for (int kk = 0; kk < 16; ++kk) {
            float a[8], b[8];
            *(float4*)&a[0] = *(const float4*)&As[kk][tm0];
            *(float4*)&a[4] = *(const float4*)&As[kk][tm0 + 4];
            *(float4*)&b[0] = *(const float4*)&Bs[kk][tn0];
            *(float4*)&b[4] = *(const float4*)&Bs[kk][tn0 + 4];
#pragma unroll
            for (int i = 0; i < 8; ++i)
#pragma unroll
                for (int j = 0; j < 8; ++j)
                    acc[i][j] = fmaf(a[i], b[j], acc[i][j]);
        }
        __syncthreads();
    }

    // epilogue
#pragma unroll
    for (int j = 0; j < 8; ++j) {
        const int gn = n0 + tn0 + j;
#pragma unroll
        for (int i = 0; i < 8; ++i) {
            const int gm = m0 + tm0 + i;
            if (gm >= M) continue;
            float v = acc[i][j];
            if constexpr (MODE == 0) {
                if (gm < DINNER) C0[(size_t)gn * DINNER + gm] = v;
                else             C1[(size_t)gn * DINNER + (gm - DINNER)] = v;
            } else if constexpr (MODE == 2) {
                v += bias[gm];
                float sp = (v > 20.f) ? v : log1pf(__expf(v));
                C0[(size_t)gn * ldc + gm] = sp;
            } else {
                C0[(size_t)gn * ldc + gm] = v;
            }
        }
    }
}

// ---------------------------------------------------------------------------
// Causal depthwise conv (width 4) + SiLU.
// x, xact layout: [tok = l*2+b][e], tok-major.  x[l<0] = 0.
// xc[l] = sum_k w[e][k] * x[l-3+k];  xact = silu(xc)
// ---------------------------------------------------------------------------
__global__ __launch_bounds__(256)
void conv_silu(const float* __restrict__ x, const float* __restrict__ conv_w,
               float* __restrict__ xact)
{
    const size_t idx = (size_t)blockIdx.x * 256 + threadIdx.x;  // over NTOK*DINNER
    const int e = (int)(idx & (DINNER - 1));
    const int n = (int)(idx >> 12);   // tok index (DINNER = 2^12)

    const float4 w = *(const float4*)&conv_w[e * 4];
    float s = w.w * x[idx];                                   // k=3 (offset 0)
    if (n >= 2) s += w.z * x[idx - (size_t)2 * DINNER];       // k=2
    if (n >= 4) s += w.y * x[idx - (size_t)4 * DINNER];       // k=1
    if (n >= 6) s += w.x * x[idx - (size_t)6 * DINNER];       // k=0
    xact[idx] = s / (1.f + __expf(-s));                       // silu
}

// ---------------------------------------------------------------------------
// Selective scan. 16 lanes per channel (b,e) — one lane per state.
// Reads delta/u/z at [tok*DINNER+e], B/C at xdbl[tok*160 + 128/144 + s].
// Writes y (gated) IN PLACE over z (each element read before written by the
// same thread at the same step -> race-free).
// grid: (DINNER/16, BATCH), block: 256 (=16 channels).
// ---------------------------------------------------------------------------
__global__ __launch_bounds__(256)
void scan_kernel(const float* __restrict__ delta, const float* __restrict__ u,
                 const float* __restrict__ xdbl, float* __restrict__ zy,
                 const float* __restrict__ A_log, const float* __restrict__ Dvec)
{
    const int b = blockIdx.y;
    const int e = blockIdx.x * 16 + (threadIdx.x >> 4);
    const int s = threadIdx.x & 15;

    const float Aval = -__expf(A_log[e * DSTATE + s]);
    const float Dv   = Dvec[e];

    float h = 0.f;
    for (int l = 0; l < L_SEQ; ++l) {
        const int tok = l * BATCH + b;
        const size_t ce = (size_t)tok * DINNER + e;
        const float dl = delta[ce];
        const float ul = u[ce];
        const float Bv = xdbl[tok * 160 + 128 + s];
        const float Cv = xdbl[tok * 160 + 144 + s];

        const float dA = __expf(dl * Aval);
        h = fmaf(dA, h, dl * ul * Bv);
        float p = h * Cv;
        p += __shfl_xor(p, 1);
        p += __shfl_xor(p, 2);
        p += __shfl_xor(p, 4);
        p += __shfl_xor(p, 8);

        if (s == 0) {
            const float zl = zy[ce];
            const float sig = 1.f / (1.f + __expf(-zl));
            zy[ce] = (p + ul * Dv) * (zl * sig);
        }
    }
}

// ---------------------------------------------------------------------------
extern "C" void kernel_launch(void* const* d_in, const int* in_sizes, int n_in,
                              void* d_out, int out_size, void* d_ws, size_t ws_size,
                              hipStream_t stream)
{
    const float* hidden    = (const float*)d_in[0];  // (L,B,DMODEL) = tok-major [tok][d]
    const float* in_proj_w = (const float*)d_in[1];  // (2*DINNER, DMODEL)
    const float* conv_w    = (const float*)d_in[2];  // (DINNER, 4)
    const float* x_proj_w  = (const float*)d_in[3];  // (160, DINNER)
    const float* dt_proj_w = (const float*)d_in[4];  // (DINNER, DTRANK)
    const float* dt_proj_b = (const float*)d_in[5];  // (DINNER)
    const float* A_log     = (const float*)d_in[6];  // (DINNER, DSTATE)
    const float* Dvec      = (const float*)d_in[7];  // (DINNER)
    const float* out_proj_w= (const float*)d_in[8];  // (DMODEL, DINNER)
    float* out = (float*)d_out;                      // (L,B,DMODEL) = [tok][m]

    // workspace layout (fp32), tok-major [tok][channel]:
    const size_t NBIG = (size_t)NTOK * DINNER;       // 16.78M floats
    float* xbuf = (float*)d_ws;          // raw x, later reused for delta
    float* zbuf = xbuf + NBIG;           // z, later overwritten by gated y
    float* xact = zbuf + NBIG;           // silu(conv(x)) = u
    float* xdbl = xact + NBIG;           // (NTOK, 160): dt_r | B | C

    // 1) in_proj: xz[e][tok] = in_proj_w @ hidden   -> split into x/z
    gemm_tn<0><<<dim3(NTOK / 128, (2 * DINNER) / 128), 256, 0, stream>>>(
        in_proj_w, hidden, xbuf, zbuf, nullptr,
        2 * DINNER, NTOK, DMODEL, DMODEL, DMODEL, DINNER);

    // 2) causal conv + silu -> xact
    conv_silu<<<(int)(NBIG / 256), 256, 0, stream>>>(xbuf, conv_w, xact);

    // 3) x_proj: xdbl[tok][0..159]
    gemm_tn<1><<<dim3(NTOK / 128, 2), 256, 0, stream>>>(
        x_proj_w, xact, xdbl, nullptr, nullptr,
        DTRANK + 2 * DSTATE, NTOK, DINNER, DINNER, DINNER, 160);

    // 4) dt_proj + softplus -> delta (reuse xbuf)
    gemm_tn<2><<<dim3(NTOK / 128, DINNER / 128), 256, 0, stream>>>(
        dt_proj_w, xdbl, xbuf, nullptr, dt_proj_b,
        DINNER, NTOK, DTRANK, DTRANK, 160, DINNER);

    // 5) selective scan + gate: y (over zbuf)
    scan_kernel<<<dim3(DINNER / 16, BATCH), 256, 0, stream>>>(
        xbuf, xact, xdbl, zbuf, A_log, Dvec);

    // 6) out_proj -> d_out
    gemm_tn<3><<<dim3(NTOK / 128, DMODEL / 128), 256, 0, stream>>>(
        out_proj_w, zbuf, out, nullptr, nullptr,
        DMODEL, NTOK, DINNER, DINNER, DINNER, DMODEL);
}

// Round 2
// 3277.457 us; speedup vs baseline: 1.4576x; 1.4576x over previous
//
#include <hip/hip_runtime.h>
#include <hip/hip_bf16.h>
#include <math.h>

#define L_SEQ   2048
#define BATCH   2
#define DMODEL  2048
#define DINNER  4096
#define DSTATE  16
#define DTRANK  128
#define NTOK    (L_SEQ * BATCH)   // 4096
#define CHUNK   64
#define NCHUNK  (L_SEQ / CHUNK)   // 32

// ---------------------------------------------------------------------------
// Generic fp32 GEMM:  C[m][n] = sum_k A[m*lda + k] * Bt[n*ldb + k]
// (unchanged from R1 — bf16 MFMA planned for next round)
// ---------------------------------------------------------------------------
template <int MODE>
__global__ __launch_bounds__(256)
void gemm_tn(const float* __restrict__ A, const float* __restrict__ Bt,
             float* __restrict__ C0, float* __restrict__ C1,
             const float* __restrict__ bias,
             int M, int N, int K, int lda, int ldb, int ldc)
{
    __shared__ __align__(16) float As[16][128];
    __shared__ __align__(16) float Bs[16][128];

    const int m0 = blockIdx.y * 128;
    const int n0 = blockIdx.x * 128;
    const int t  = threadIdx.x;
    const int r    = t >> 1;
    const int koff = (t & 1) * 8;
    const int tm0  = (t >> 4) * 8;
    const int tn0  = (t & 15) * 8;

    float acc[8][8];
#pragma unroll
    for (int i = 0; i < 8; ++i)
#pragma unroll
        for (int j = 0; j < 8; ++j) acc[i][j] = 0.f;

    for (int k0 = 0; k0 < K; k0 += 16) {
        {
            const int gm = m0 + r;
            float4 a0 = {0, 0, 0, 0}, a1 = {0, 0, 0, 0};
            if (gm < M) {
                const float* p = A + (size_t)gm * lda + k0 + koff;
                a0 = *(const float4*)p;
                a1 = *(const float4*)(p + 4);
            }
            As[koff + 0][r] = a0.x; As[koff + 1][r] = a0.y;
            As[koff + 2][r] = a0.z; As[koff + 3][r] = a0.w;
            As[koff + 4][r] = a1.x; As[koff + 5][r] = a1.y;
            As[koff + 6][r] = a1.z; As[koff + 7][r] = a1.w;
        }
        {
            const int gn = n0 + r;
            const float* p = Bt + (size_t)gn * ldb + k0 + koff;
            float4 b0 = *(const float4*)p;
            float4 b1 = *(const float4*)(p + 4);
            Bs[koff + 0][r] = b0.x; Bs[koff + 1][r] = b0.y;
            Bs[koff + 2][r] = b0.z; Bs[koff + 3][r] = b0.w;
            Bs[koff + 4][r] = b1.x; Bs[koff + 5][r] = b1.y;
            Bs[koff + 6][r] = b1.z; Bs[koff + 7][r] = b1.w;
        }
        __syncthreads();

#pragma unroll
        for (int kk = 0; kk < 16; ++kk) {
            float a[8], b[8];
            *(float4*)&a[0] = *(const float4*)&As[kk][tm0];
            *(float4*)&a[4] = *(const float4*)&As[kk][tm0 + 4];
            *(float4*)&b[0] = *(const float4*)&Bs[kk][tn0];
            *(float4*)&b[4] = *(const float4*)&Bs[kk][tn0 + 4];
#pragma unroll
            for (int i = 0; i < 8; ++i)
#pragma unroll
                for (int j = 0; j < 8; ++j)
                    acc[i][j] = fmaf(a[i], b[j], acc[i][j]);
        }
        __syncthreads();
    }

#pragma unroll
    for (int j = 0; j < 8; ++j) {
        const int gn = n0 + tn0 + j;
#pragma unroll
        for (int i = 0; i < 8; ++i) {
            const int gm = m0 + tm0 + i;
            if (gm >= M) continue;
            float v = acc[i][j];
            if constexpr (MODE == 0) {
                if (gm < DINNER) C0[(size_t)gn * DINNER + gm] = v;
                else             C1[(size_t)gn * DINNER + (gm - DINNER)] = v;
            } else if constexpr (MODE == 2) {
                v += bias[gm];
                float sp = (v > 20.f) ? v : log1pf(__expf(v));
                C0[(size_t)gn * ldc + gm] = sp;
            } else {
                C0[(size_t)gn * ldc + gm] = v;
            }
        }
    }
}

// ---------------------------------------------------------------------------
// Causal depthwise conv (width 4) + SiLU (unchanged).
// ---------------------------------------------------------------------------
__global__ __launch_bounds__(256)
void conv_silu(const float* __restrict__ x, const float* __restrict__ conv_w,
               float* __restrict__ xact)
{
    const size_t idx = (size_t)blockIdx.x * 256 + threadIdx.x;
    const int e = (int)(idx & (DINNER - 1));
    const int n = (int)(idx >> 12);

    const float4 w = *(const float4*)&conv_w[e * 4];
    float s = w.w * x[idx];
    if (n >= 2) s += w.z * x[idx - (size_t)2 * DINNER];
    if (n >= 4) s += w.y * x[idx - (size_t)4 * DINNER];
    if (n >= 6) s += w.x * x[idx - (size_t)6 * DINNER];
    xact[idx] = s / (1.f + __expf(-s));
}

// ---------------------------------------------------------------------------
// Chunked selective scan.
// h[l] = dA[l]*h[l-1] + (delta*u)[l]*B[l]   is affine in h -> per-chunk
// summary (P = prod dA, S = local scan result), sequential combine over
// NCHUNK summaries, then per-chunk replay producing gated y.
//
// Phase A: one THREAD per channel e (coalesced delta/u loads), P[16]/S[16]
//          in registers, B staged in LDS.  grid (DINNER/256, NCHUNK, BATCH).
// ---------------------------------------------------------------------------
__global__ __launch_bounds__(256)
void scan_partial(const float* __restrict__ delta, const float* __restrict__ u,
                  const float* __restrict__ xdbl, const float* __restrict__ A_log,
                  float2* __restrict__ PS)
{
    const int e     = blockIdx.x * 256 + threadIdx.x;
    const int chunk = blockIdx.y;
    const int b     = blockIdx.z;

    __shared__ float BC[CHUNK][32];   // [l_local][0..15]=B, [16..31]=C (C unused here)
    for (int i = threadIdx.x; i < CHUNK * 32; i += 256) {
        const int ll = i >> 5, f = i & 31;
        const int tok = (chunk * CHUNK + ll) * BATCH + b;
        BC[ll][f] = xdbl[tok * 160 + 128 + f];
    }

    float Av[16];
#pragma unroll
    for (int s = 0; s < 16; s += 4) {
        float4 t = *(const float4*)&A_log[e * 16 + s];
        Av[s] = -__expf(t.x); Av[s + 1] = -__expf(t.y);
        Av[s + 2] = -__expf(t.z); Av[s + 3] = -__expf(t.w);
    }
    __syncthreads();

    float P[16], S[16];
#pragma unroll
    for (int s = 0; s < 16; ++s) { P[s] = 1.f; S[s] = 0.f; }

#pragma unroll 4
    for (int ll = 0; ll < CHUNK; ++ll) {
        const int tok = (chunk * CHUNK + ll) * BATCH + b;
        const size_t ce = (size_t)tok * DINNER + e;
        const float dl = delta[ce];
        const float du = dl * u[ce];
#pragma unroll
        for (int s = 0; s < 16; ++s) {
            const float dA = __expf(dl * Av[s]);
            S[s] = fmaf(dA, S[s], du * BC[ll][s]);
            P[s] *= dA;
        }
    }

    float2* outp = PS + ((size_t)(chunk * BATCH + b) * DINNER + e) * 16;
#pragma unroll
    for (int s = 0; s < 16; ++s) outp[s] = make_float2(P[s], S[s]);
}

// ---------------------------------------------------------------------------
// Phase B: sequential combine across chunks. One thread per (b,e,s).
// All loads independent of the carried h -> fully pipelined.
// Writes h at the START of each chunk.
// ---------------------------------------------------------------------------
__global__ __launch_bounds__(256)
void scan_combine(const float2* __restrict__ PS, float* __restrict__ Hinit)
{
    const size_t pos = (size_t)blockIdx.x * 256 + threadIdx.x; // (b*DINNER+e)*16+s
    const size_t stride = (size_t)BATCH * DINNER * 16;
    float h = 0.f;
#pragma unroll
    for (int c = 0; c < NCHUNK; ++c) {
        Hinit[c * stride + pos] = h;
        const float2 ps = PS[c * stride + pos];
        h = fmaf(ps.x, h, ps.y);
    }
}

// ---------------------------------------------------------------------------
// Phase C: replay each chunk from Hinit, y = <h,C>, fuse D-term + SiLU gate.
// Writes gated y in place over z.
// ---------------------------------------------------------------------------
__global__ __launch_bounds__(256)
void scan_final(const float* __restrict__ delta, const float* __restrict__ u,
                const float* __restrict__ xdbl, const float* __restrict__ Hinit,
                float* __restrict__ zy, const float* __restrict__ A_log,
                const float* __restrict__ Dvec)
{
    const int e     = blockIdx.x * 256 + threadIdx.x;
    const int chunk = blockIdx.y;
    const int b     = blockIdx.z;

    __shared__ float BC[CHUNK][32];
    for (int i = threadIdx.x; i < CHUNK * 32; i += 256) {
        const int ll = i >> 5, f = i & 31;
        const int tok = (chunk * CHUNK + ll) * BATCH + b;
        BC[ll][f] = xdbl[tok * 160 + 128 + f];
    }

    float Av[16];
#pragma unroll
    for (int s = 0; s < 16; s += 4) {
        float4 t = *(const float4*)&A_log[e * 16 + s];
        Av[s] = -__expf(t.x); Av[s + 1] = -__expf(t.y);
        Av[s + 2] = -__expf(t.z); Av[s + 3] = -__expf(t.w);
    }
    const float Dv = Dvec[e];

    float h[16];
    const float* hi = Hinit + (size_t)chunk * BATCH * DINNER * 16
                            + ((size_t)b * DINNER + e) * 16;
#pragma unroll
    for (int s = 0; s < 16; s += 4) *(float4*)&h[s] = *(const float4*)&hi[s];
    __syncthreads();

#pragma unroll 2
    for (int ll = 0; ll < CHUNK; ++ll) {
        const int tok = (chunk * CHUNK + ll) * BATCH + b;
        const size_t ce = (size_t)tok * DINNER + e;
        const float dl = delta[ce];
        const float ul = u[ce];
        const float du = dl * ul;
        float y = 0.f;
#pragma unroll
        for (int s = 0; s < 16; ++s) {
            const float dA = __expf(dl * Av[s]);
            h[s] = fmaf(dA, h[s], du * BC[ll][s]);
            y = fmaf(h[s], BC[ll][16 + s], y);
        }
        const float zl = zy[ce];
        const float sig = 1.f / (1.f + __expf(-zl));
        zy[ce] = (y + ul * Dv) * (zl * sig);
    }
}

// ---------------------------------------------------------------------------
extern "C" void kernel_launch(void* const* d_in, const int* in_sizes, int n_in,
                              void* d_out, int out_size, void* d_ws, size_t ws_size,
                              hipStream_t stream)
{
    const float* hidden    = (const float*)d_in[0];
    const float* in_proj_w = (const float*)d_in[1];
    const float* conv_w    = (const float*)d_in[2];
    const float* x_proj_w  = (const float*)d_in[3];
    const float* dt_proj_w = (const float*)d_in[4];
    const float* dt_proj_b = (const float*)d_in[5];
    const float* A_log     = (const float*)d_in[6];
    const float* Dvec      = (const float*)d_in[7];
    const float* out_proj_w= (const float*)d_in[8];
    float* out = (float*)d_out;

    const size_t NBIG = (size_t)NTOK * DINNER;
    float* xbuf = (float*)d_ws;          // raw x -> later delta
    float* zbuf = xbuf + NBIG;           // z -> gated y
    float* xact = zbuf + NBIG;           // silu(conv(x)) = u
    float* xdbl = xact + NBIG;           // (NTOK,160)
    float2* PS  = (float2*)(xdbl + (size_t)NTOK * 160);          // 33.5 MB
    float* Hinit = (float*)(PS + (size_t)NCHUNK * BATCH * DINNER * 16); // 16.8 MB

    // 1) in_proj
    gemm_tn<0><<<dim3(NTOK / 128, (2 * DINNER) / 128), 256, 0, stream>>>(
        in_proj_w, hidden, xbuf, zbuf, nullptr,
        2 * DINNER, NTOK, DMODEL, DMODEL, DMODEL, DINNER);

    // 2) conv + silu
    conv_silu<<<(int)(NBIG / 256), 256, 0, stream>>>(xbuf, conv_w, xact);

    // 3) x_proj
    gemm_tn<1><<<dim3(NTOK / 128, 2), 256, 0, stream>>>(
        x_proj_w, xact, xdbl, nullptr, nullptr,
        DTRANK + 2 * DSTATE, NTOK, DINNER, DINNER, DINNER, 160);

    // 4) dt_proj + softplus -> delta
    gemm_tn<2><<<dim3(NTOK / 128, DINNER / 128), 256, 0, stream>>>(
        dt_proj_w, xdbl, xbuf, nullptr, dt_proj_b,
        DINNER, NTOK, DTRANK, DTRANK, 160, DINNER);

    // 5) chunked scan
    scan_partial<<<dim3(DINNER / 256, NCHUNK, BATCH), 256, 0, stream>>>(
        xbuf, xact, xdbl, A_log, PS);
    scan_combine<<<(BATCH * DINNER * 16) / 256, 256, 0, stream>>>(PS, Hinit);
    scan_final<<<dim3(DINNER / 256, NCHUNK, BATCH), 256, 0, stream>>>(
        xbuf, xact, xdbl, Hinit, zbuf, A_log, Dvec);

    // 6) out_proj
    gemm_tn<3><<<dim3(NTOK / 128, DMODEL / 128), 256, 0, stream>>>(
        out_proj_w, zbuf, out, nullptr, nullptr,
        DMODEL, NTOK, DINNER, DINNER, DINNER, DMODEL);
}

// Round 4
// 858.111 us; speedup vs baseline: 5.5670x; 3.8194x over previous
//
#include <hip/hip_runtime.h>
#include <hip/hip_bf16.h>
#include <math.h>

#define L_SEQ   2048
#define BATCH   2
#define DMODEL  2048
#define DINNER  4096
#define DSTATE  16
#define DTRANK  128
#define NTOK    (L_SEQ * BATCH)   // 4096
#define CHUNK   128
#define NCHUNK  (L_SEQ / CHUNK)   // 16

typedef __attribute__((ext_vector_type(8))) __bf16 bf16x8;
typedef __attribute__((ext_vector_type(4))) float f32x4;

__device__ __forceinline__ __bf16 f2bf(float f) {
    unsigned u = __builtin_bit_cast(unsigned, f);
    unsigned r = (u + 0x7FFFu + ((u >> 16) & 1u)) >> 16;
    return __builtin_bit_cast(__bf16, (unsigned short)r);
}

__device__ __forceinline__ void load_lds16(const void* gsrc, void* lds) {
    __builtin_amdgcn_global_load_lds(
        (const __attribute__((address_space(1))) unsigned int*)gsrc,
        (__attribute__((address_space(3))) unsigned int*)lds, 16, 0, 0);
}

// ---------------------------------------------------------------------------
// bf16 MFMA GEMM (m97 structure): C[m][n] = sum_k A[m][k] * Bt[n][k]
// 128x128 tile, BK=64, 4 waves (2x2 of 64x64), mfma_f32_16x16x32_bf16,
// global_load_lds width 16, linear LDS.
// MODE 0: m<DINNER -> C0 fp32 (x); else C1b bf16 (z).  ldc=DINNER both.
// MODE 1: C0[n*ldc+m] fp32, guarded m < Mvalid.
// ---------------------------------------------------------------------------
template <int MODE>
__global__ __launch_bounds__(256)
void gemm_bf16(const __bf16* __restrict__ A, const __bf16* __restrict__ Bt,
               float* __restrict__ C0, __bf16* __restrict__ C1b,
               int Mvalid, int K, int lda, int ldb, int ldc)
{
    __shared__ __align__(16) __bf16 As[128 * 64];
    __shared__ __align__(16) __bf16 Bs[128 * 64];

    const int t  = threadIdx.x;
    const int m0 = blockIdx.y * 128;
    const int n0 = blockIdx.x * 128;
    const int l  = t & 63;
    const int w  = t >> 6;
    const int wr = (w >> 1) * 64;
    const int wc = (w & 1) * 64;
    const int lrow = t >> 3;
    const int lk   = (t & 7) * 8;

    f32x4 acc[4][4];
#pragma unroll
    for (int i = 0; i < 4; ++i)
#pragma unroll
        for (int j = 0; j < 4; ++j) acc[i][j] = (f32x4){0.f, 0.f, 0.f, 0.f};

    for (int k0 = 0; k0 < K; k0 += 64) {
#pragma unroll
        for (int q = 0; q < 4; ++q) {
            const int row = q * 32 + lrow;
            load_lds16(A  + (size_t)(m0 + row) * lda + k0 + lk, &As[row * 64 + lk]);
            load_lds16(Bt + (size_t)(n0 + row) * ldb + k0 + lk, &Bs[row * 64 + lk]);
        }
        __syncthreads();

#pragma unroll
        for (int kk = 0; kk < 2; ++kk) {
            const int krd = kk * 32 + (l >> 4) * 8;
            bf16x8 a[4], b[4];
#pragma unroll
            for (int i = 0; i < 4; ++i) {
                a[i] = *(const bf16x8*)&As[(wr + i * 16 + (l & 15)) * 64 + krd];
                b[i] = *(const bf16x8*)&Bs[(wc + i * 16 + (l & 15)) * 64 + krd];
            }
#pragma unroll
            for (int i = 0; i < 4; ++i)
#pragma unroll
                for (int j = 0; j < 4; ++j)
                    acc[i][j] = __builtin_amdgcn_mfma_f32_16x16x32_bf16(
                        a[i], b[j], acc[i][j], 0, 0, 0);
        }
        __syncthreads();
    }

    const int rbase = (l >> 4) * 4;
    const int cbase = l & 15;
#pragma unroll
    for (int i = 0; i < 4; ++i) {
#pragma unroll
        for (int j = 0; j < 4; ++j) {
#pragma unroll
            for (int r = 0; r < 4; ++r) {
                const int m = m0 + wr + i * 16 + rbase + r;
                const int n = n0 + wc + j * 16 + cbase;
                const float v = acc[i][j][r];
                if constexpr (MODE == 0) {
                    if (m < DINNER) C0[(size_t)n * DINNER + m] = v;
                    else            C1b[(size_t)n * DINNER + (m - DINNER)] = f2bf(v);
                } else {
                    if (m < Mvalid) C0[(size_t)n * ldc + m] = v;
                }
            }
        }
    }
}

// ---------------------------------------------------------------------------
// fp32 GEMM (dt_proj only). MODE 2: softplus(v + bias[m]) -> C0[n*ldc+m].
// ---------------------------------------------------------------------------
template <int MODE>
__global__ __launch_bounds__(256)
void gemm_tn(const float* __restrict__ A, const float* __restrict__ Bt,
             float* __restrict__ C0, float* __restrict__ C1,
             const float* __restrict__ bias,
             int M, int N, int K, int lda, int ldb, int ldc)
{
    __shared__ __align__(16) float As[16][128];
    __shared__ __align__(16) float Bs[16][128];

    const int m0 = blockIdx.y * 128;
    const int n0 = blockIdx.x * 128;
    const int t  = threadIdx.x;
    const int r    = t >> 1;
    const int koff = (t & 1) * 8;
    const int tm0  = (t >> 4) * 8;
    const int tn0  = (t & 15) * 8;

    float acc[8][8];
#pragma unroll
    for (int i = 0; i < 8; ++i)
#pragma unroll
        for (int j = 0; j < 8; ++j) acc[i][j] = 0.f;

    for (int k0 = 0; k0 < K; k0 += 16) {
        {
            const int gm = m0 + r;
            float4 a0 = {0, 0, 0, 0}, a1 = {0, 0, 0, 0};
            if (gm < M) {
                const float* p = A + (size_t)gm * lda + k0 + koff;
                a0 = *(const float4*)p;
                a1 = *(const float4*)(p + 4);
            }
            As[koff + 0][r] = a0.x; As[koff + 1][r] = a0.y;
            As[koff + 2][r] = a0.z; As[koff + 3][r] = a0.w;
            As[koff + 4][r] = a1.x; As[koff + 5][r] = a1.y;
            As[koff + 6][r] = a1.z; As[koff + 7][r] = a1.w;
        }
        {
            const int gn = n0 + r;
            const float* p = Bt + (size_t)gn * ldb + k0 + koff;
            float4 b0 = *(const float4*)p;
            float4 b1 = *(const float4*)(p + 4);
            Bs[koff + 0][r] = b0.x; Bs[koff + 1][r] = b0.y;
            Bs[koff + 2][r] = b0.z; Bs[koff + 3][r] = b0.w;
            Bs[koff + 4][r] = b1.x; Bs[koff + 5][r] = b1.y;
            Bs[koff + 6][r] = b1.z; Bs[koff + 7][r] = b1.w;
        }
        __syncthreads();

#pragma unroll
        for (int kk = 0; kk < 16; ++kk) {
            float a[8], b[8];
            *(float4*)&a[0] = *(const float4*)&As[kk][tm0];
            *(float4*)&a[4] = *(const float4*)&As[kk][tm0 + 4];
            *(float4*)&b[0] = *(const float4*)&Bs[kk][tn0];
            *(float4*)&b[4] = *(const float4*)&Bs[kk][tn0 + 4];
#pragma unroll
            for (int i = 0; i < 8; ++i)
#pragma unroll
                for (int j = 0; j < 8; ++j)
                    acc[i][j] = fmaf(a[i], b[j], acc[i][j]);
        }
        __syncthreads();
    }

#pragma unroll
    for (int j = 0; j < 8; ++j) {
        const int gn = n0 + tn0 + j;
#pragma unroll
        for (int i = 0; i < 8; ++i) {
            const int gm = m0 + tm0 + i;
            if (gm >= M) continue;
            float v = acc[i][j];
            if constexpr (MODE == 2) {
                v += bias[gm];
                float sp = (v > 20.f) ? v : log1pf(__expf(v));
                C0[(size_t)gn * ldc + gm] = sp;
            } else {
                C0[(size_t)gn * ldc + gm] = v;
            }
        }
    }
}

// ---------------------------------------------------------------------------
__global__ __launch_bounds__(256)
void cvt_bf16(const float* __restrict__ in, __bf16* __restrict__ out, int n8)
{
    const int i = blockIdx.x * 256 + threadIdx.x;
    if (i >= n8) return;
    const size_t base = (size_t)i * 8;
    const float4 a = *(const float4*)&in[base];
    const float4 b = *(const float4*)&in[base + 4];
    __align__(16) __bf16 o[8];
    o[0] = f2bf(a.x); o[1] = f2bf(a.y); o[2] = f2bf(a.z); o[3] = f2bf(a.w);
    o[4] = f2bf(b.x); o[5] = f2bf(b.y); o[6] = f2bf(b.z); o[7] = f2bf(b.w);
    *(bf16x8*)&out[base] = *(const bf16x8*)o;
}

__global__ __launch_bounds__(256)
void cvt_xproj(const float* __restrict__ in, __bf16* __restrict__ out)
{
    const int i = blockIdx.x * 256 + threadIdx.x;
    const size_t base = (size_t)i * 8;
    const int row = (int)(base >> 12);
    __align__(16) __bf16 o[8];
    if (row < 160) {
        const float4 a = *(const float4*)&in[base];
        const float4 b = *(const float4*)&in[base + 4];
        o[0] = f2bf(a.x); o[1] = f2bf(a.y); o[2] = f2bf(a.z); o[3] = f2bf(a.w);
        o[4] = f2bf(b.x); o[5] = f2bf(b.y); o[6] = f2bf(b.z); o[7] = f2bf(b.w);
    } else {
#pragma unroll
        for (int k = 0; k < 8; ++k) o[k] = f2bf(0.f);
    }
    *(bf16x8*)&out[base] = *(const bf16x8*)o;
}

// ---------------------------------------------------------------------------
// Causal depthwise conv (width 4) + SiLU -> bf16 u only.
// ---------------------------------------------------------------------------
__global__ __launch_bounds__(256)
void conv_silu(const float* __restrict__ x, const float* __restrict__ conv_w,
               __bf16* __restrict__ xact_bf)
{
    const size_t idx = (size_t)blockIdx.x * 256 + threadIdx.x;
    const int e = (int)(idx & (DINNER - 1));
    const int n = (int)(idx >> 12);

    const float4 w = *(const float4*)&conv_w[e * 4];
    float s = w.w * x[idx];
    if (n >= 2) s += w.z * x[idx - (size_t)2 * DINNER];
    if (n >= 4) s += w.y * x[idx - (size_t)4 * DINNER];
    if (n >= 6) s += w.x * x[idx - (size_t)6 * DINNER];
    const float v = s / (1.f + __expf(-s));
    xact_bf[idx] = f2bf(v);
}

// ---------------------------------------------------------------------------
// Chunked selective scan (CHUNK=128, NCHUNK=16). u is bf16.
// ---------------------------------------------------------------------------
__global__ __launch_bounds__(256)
void scan_partial(const float* __restrict__ delta, const __bf16* __restrict__ u,
                  const float* __restrict__ xdbl, const float* __restrict__ A_log,
                  float2* __restrict__ PS)
{
    const int e     = blockIdx.x * 256 + threadIdx.x;
    const int chunk = blockIdx.y;
    const int b     = blockIdx.z;

    __shared__ float BC[CHUNK][32];
    for (int i = threadIdx.x; i < CHUNK * 32; i += 256) {
        const int ll = i >> 5, f = i & 31;
        const int tok = (chunk * CHUNK + ll) * BATCH + b;
        BC[ll][f] = xdbl[tok * 160 + 128 + f];
    }

    float Av[16];
#pragma unroll
    for (int s = 0; s < 16; s += 4) {
        float4 t = *(const float4*)&A_log[e * 16 + s];
        Av[s] = -__expf(t.x); Av[s + 1] = -__expf(t.y);
        Av[s + 2] = -__expf(t.z); Av[s + 3] = -__expf(t.w);
    }
    __syncthreads();

    float P[16], S[16];
#pragma unroll
    for (int s = 0; s < 16; ++s) { P[s] = 1.f; S[s] = 0.f; }

#pragma unroll 4
    for (int ll = 0; ll < CHUNK; ++ll) {
        const int tok = (chunk * CHUNK + ll) * BATCH + b;
        const size_t ce = (size_t)tok * DINNER + e;
        const float dl = delta[ce];
        const float du = dl * (float)u[ce];
#pragma unroll
        for (int s = 0; s < 16; ++s) {
            const float dA = __expf(dl * Av[s]);
            S[s] = fmaf(dA, S[s], du * BC[ll][s]);
            P[s] *= dA;
        }
    }

    float2* outp = PS + ((size_t)(chunk * BATCH + b) * DINNER + e) * 16;
#pragma unroll
    for (int s = 0; s < 16; ++s) outp[s] = make_float2(P[s], S[s]);
}

__global__ __launch_bounds__(256)
void scan_combine(const float2* __restrict__ PS, float* __restrict__ Hinit)
{
    const size_t pos = (size_t)blockIdx.x * 256 + threadIdx.x;
    const size_t stride = (size_t)BATCH * DINNER * 16;
    float h = 0.f;
#pragma unroll
    for (int c = 0; c < NCHUNK; ++c) {
        Hinit[c * stride + pos] = h;
        const float2 ps = PS[c * stride + pos];
        h = fmaf(ps.x, h, ps.y);
    }
}

// Phase C: replay, y = <h,C>, D-term + SiLU(z_bf) gate, emit bf16 y.
__global__ __launch_bounds__(256)
void scan_final(const float* __restrict__ delta, const __bf16* __restrict__ u,
                const float* __restrict__ xdbl, const float* __restrict__ Hinit,
                const __bf16* __restrict__ z_bf, __bf16* __restrict__ y_bf,
                const float* __restrict__ A_log, const float* __restrict__ Dvec)
{
    const int e     = blockIdx.x * 256 + threadIdx.x;
    const int chunk = blockIdx.y;
    const int b     = blockIdx.z;

    __shared__ float BC[CHUNK][32];
    for (int i = threadIdx.x; i < CHUNK * 32; i += 256) {
        const int ll = i >> 5, f = i & 31;
        const int tok = (chunk * CHUNK + ll) * BATCH + b;
        BC[ll][f] = xdbl[tok * 160 + 128 + f];
    }

    float Av[16];
#pragma unroll
    for (int s = 0; s < 16; s += 4) {
        float4 t = *(const float4*)&A_log[e * 16 + s];
        Av[s] = -__expf(t.x); Av[s + 1] = -__expf(t.y);
        Av[s + 2] = -__expf(t.z); Av[s + 3] = -__expf(t.w);
    }
    const float Dv = Dvec[e];

    float h[16];
    const float* hi = Hinit + (size_t)chunk * BATCH * DINNER * 16
                            + ((size_t)b * DINNER + e) * 16;
#pragma unroll
    for (int s = 0; s < 16; s += 4) *(float4*)&h[s] = *(const float4*)&hi[s];
    __syncthreads();

#pragma unroll 2
    for (int ll = 0; ll < CHUNK; ++ll) {
        const int tok = (chunk * CHUNK + ll) * BATCH + b;
        const size_t ce = (size_t)tok * DINNER + e;
        const float dl = delta[ce];
        const float ul = (float)u[ce];
        const float du = dl * ul;
        float y = 0.f;
#pragma unroll
        for (int s = 0; s < 16; ++s) {
            const float dA = __expf(dl * Av[s]);
            h[s] = fmaf(dA, h[s], du * BC[ll][s]);
            y = fmaf(h[s], BC[ll][16 + s], y);
        }
        const float zl = (float)z_bf[ce];
        const float sig = 1.f / (1.f + __expf(-zl));
        y_bf[ce] = f2bf((y + ul * Dv) * (zl * sig));
    }
}

// ---------------------------------------------------------------------------
extern "C" void kernel_launch(void* const* d_in, const int* in_sizes, int n_in,
                              void* d_out, int out_size, void* d_ws, size_t ws_size,
                              hipStream_t stream)
{
    const float* hidden    = (const float*)d_in[0];
    const float* in_proj_w = (const float*)d_in[1];
    const float* conv_w    = (const float*)d_in[2];
    const float* x_proj_w  = (const float*)d_in[3];
    const float* dt_proj_w = (const float*)d_in[4];
    const float* dt_proj_b = (const float*)d_in[5];
    const float* A_log     = (const float*)d_in[6];
    const float* Dvec      = (const float*)d_in[7];
    const float* out_proj_w= (const float*)d_in[8];
    float* out = (float*)d_out;

    // -------- workspace layout (239,599,616 B total; R2's passing layout was
    // 254,279,680 B, so this fits the same budget). Lifetime aliasing:
    //   G region: w_in_bf (steps 0-1)  -> PS + Hinit (steps 5a-5c)
    char* p = (char*)d_ws;
    const size_t NBIG = (size_t)NTOK * DINNER;           // 16.78M elems
    float*  xbuf    = (float*)p;                 p += NBIG * 4;          // x -> delta
    __bf16* z_bf    = (__bf16*)p;                p += NBIG * 2;          // z
    __bf16* xact_bf = (__bf16*)p;                p += NBIG * 2;          // u
    float*  xdbl    = (float*)p;                 p += (size_t)NTOK * 160 * 4;
    __bf16* w_xp_bf = (__bf16*)p;                p += (size_t)256 * DINNER * 2;
    __bf16* w_out_bf= (__bf16*)p;                p += (size_t)DMODEL * DINNER * 2;
    char*   G       = p;                         p += (size_t)2 * DINNER * DMODEL * 2; // 33.5MB
    __bf16* hid_bf  = (__bf16*)p;                p += (size_t)NTOK * DMODEL * 2;
    __bf16* y_bf    = (__bf16*)p;                p += NBIG * 2;
    const size_t required = (size_t)(p - (char*)d_ws);
    if (ws_size < required) return;  // fail loudly (poisoned d_out), not a fault

    __bf16* w_in_bf = (__bf16*)G;
    float2* PS      = (float2*)G;                                   // 16.78MB
    float*  Hinit   = (float*)(G + (size_t)NCHUNK * BATCH * DINNER * 16 * 8);

    // 0) conversions to bf16
    cvt_bf16<<<(int)(NTOK * DMODEL / 8 / 256), 256, 0, stream>>>(hidden, hid_bf, NTOK * DMODEL / 8);
    cvt_bf16<<<(int)(2 * DINNER * DMODEL / 8 / 256), 256, 0, stream>>>(in_proj_w, w_in_bf, 2 * DINNER * DMODEL / 8);
    cvt_bf16<<<(int)(DMODEL * DINNER / 8 / 256), 256, 0, stream>>>(out_proj_w, w_out_bf, DMODEL * DINNER / 8);
    cvt_xproj<<<(int)(256 * DINNER / 8 / 256), 256, 0, stream>>>(x_proj_w, w_xp_bf);

    // 1) in_proj (bf16 MFMA): x (fp32) | z (bf16)
    gemm_bf16<0><<<dim3(NTOK / 128, (2 * DINNER) / 128), 256, 0, stream>>>(
        w_in_bf, hid_bf, xbuf, z_bf, 2 * DINNER, DMODEL, DMODEL, DMODEL, DINNER);

    // 2) conv + silu -> u (bf16)
    conv_silu<<<(int)(NBIG / 256), 256, 0, stream>>>(xbuf, conv_w, xact_bf);

    // 3) x_proj (bf16 MFMA, M padded 160->256)
    gemm_bf16<1><<<dim3(NTOK / 128, 2), 256, 0, stream>>>(
        w_xp_bf, xact_bf, xdbl, nullptr, 160, DINNER, DINNER, DINNER, 160);

    // 4) dt_proj + softplus (fp32) -> delta (over xbuf)
    gemm_tn<2><<<dim3(NTOK / 128, DINNER / 128), 256, 0, stream>>>(
        dt_proj_w, xdbl, xbuf, nullptr, dt_proj_b,
        DINNER, NTOK, DTRANK, DTRANK, 160, DINNER);

    // 5) chunked scan (PS/Hinit overwrite w_in_bf — dead after step 1)
    scan_partial<<<dim3(DINNER / 256, NCHUNK, BATCH), 256, 0, stream>>>(
        xbuf, xact_bf, xdbl, A_log, PS);
    scan_combine<<<(BATCH * DINNER * 16) / 256, 256, 0, stream>>>(PS, Hinit);
    scan_final<<<dim3(DINNER / 256, NCHUNK, BATCH), 256, 0, stream>>>(
        xbuf, xact_bf, xdbl, Hinit, z_bf, y_bf, A_log, Dvec);

    // 6) out_proj (bf16 MFMA) -> fp32 out
    gemm_bf16<1><<<dim3(NTOK / 128, DMODEL / 128), 256, 0, stream>>>(
        w_out_bf, y_bf, out, nullptr, DMODEL, DINNER, DINNER, DINNER, DMODEL);
}

// Round 5
// 767.853 us; speedup vs baseline: 6.2214x; 1.1175x over previous
//
#include <hip/hip_runtime.h>
#include <hip/hip_bf16.h>
#include <math.h>

#define L_SEQ   2048
#define BATCH   2
#define DMODEL  2048
#define DINNER  4096
#define DSTATE  16
#define DTRANK  128
#define NTOK    (L_SEQ * BATCH)   // 4096
#define CHUNK   128
#define NCHUNK  (L_SEQ / CHUNK)   // 16

typedef __attribute__((ext_vector_type(8))) __bf16 bf16x8;
typedef __attribute__((ext_vector_type(4))) float f32x4;

__device__ __forceinline__ __bf16 f2bf(float f) {
    unsigned u = __builtin_bit_cast(unsigned, f);
    unsigned r = (u + 0x7FFFu + ((u >> 16) & 1u)) >> 16;
    return __builtin_bit_cast(__bf16, (unsigned short)r);
}

__device__ __forceinline__ void load_lds16(const void* gsrc, void* lds) {
    __builtin_amdgcn_global_load_lds(
        (const __attribute__((address_space(1))) unsigned int*)gsrc,
        (__attribute__((address_space(3))) unsigned int*)lds, 16, 0, 0);
}

// Stage one 128x64 bf16 half-tile (16 KiB) with 512 threads x 2 loads.
// LDS dest is LINEAR (row*64 + tcol8); the SOURCE column is inverse-swizzled
// (scol = tcol8 ^ ((trow&7)<<3)) so that swizzled ds_reads see logical data.
__device__ __forceinline__ void stage_half(const __bf16* g, int ld,
                                           __bf16* lh, int trow, int tcol8, int scol)
{
    load_lds16(g + (size_t)trow        * ld + scol, lh +  trow       * 64 + tcol8);
    load_lds16(g + (size_t)(trow + 64) * ld + scol, lh + (trow + 64) * 64 + tcol8);
}

// ---------------------------------------------------------------------------
// 8-phase-style 256x256 bf16 MFMA GEMM.  C[m][n] = sum_k A[m][k]*Bt[n][k].
// 512 threads = 8 waves (2M x 4N), per-wave 128x64 output, BK=64.
// LDS: 2 tile-buffers x {A-h0,A-h1,B-h0,B-h1} x 16KiB = 128 KiB.
// Counted vmcnt(4) at tile boundaries (drain only before the last tile).
// Requires: M%256==0, N%256==0, K%64==0, K>=128, grid = (M/256)*(N/256), %8==0.
// MODE 0: m<DINNER -> C0 fp32; else C1b bf16 (both ldc=DINNER)   [in_proj]
// MODE 1: C0[n*ldc+m] fp32                                       [out_proj]
// ---------------------------------------------------------------------------
template <int MODE>
__global__ __launch_bounds__(512, 1)
void gemm8(const __bf16* __restrict__ A, const __bf16* __restrict__ Bt,
           float* __restrict__ C0, __bf16* __restrict__ C1b,
           int K, int lda, int ldb, int ldc, int nbn)
{
    __shared__ __align__(16) __bf16 lds8[2 * 4 * 8192];   // 128 KiB

    const int t = threadIdx.x;
    // XCD-bijective swizzle (gridDim.x % 8 == 0 at all call sites)
    const int nwg = gridDim.x;
    const int swz = (blockIdx.x & 7) * (nwg >> 3) + (blockIdx.x >> 3);
    const int m0 = (swz / nbn) * 256;
    const int n0 = (swz % nbn) * 256;

    const int l      = t & 63;
    const int w      = t >> 6;
    const int wm     = w >> 2;        // 0..1
    const int wn     = w & 3;         // 0..3
    const int lane15 = l & 15;
    const int lhi    = l >> 4;        // 0..3
    const int trow   = t >> 3;        // 0..63 staging row
    const int tcol8  = (t & 7) * 8;   // staging col (elements, linear LDS)
    const int scol   = tcol8 ^ ((trow & 7) << 3);  // inverse-swizzled src col

    const __bf16* Ah0 = A  + (size_t)m0 * lda;
    const __bf16* Ah1 = A  + (size_t)(m0 + 128) * lda;
    const __bf16* Bh0 = Bt + (size_t)n0 * ldb;
    const __bf16* Bh1 = Bt + (size_t)(n0 + 128) * ldb;

    const int NT = K >> 6;

    f32x4 acc[8][4];
#pragma unroll
    for (int i = 0; i < 8; ++i)
#pragma unroll
        for (int j = 0; j < 4; ++j) acc[i][j] = (f32x4){0.f, 0.f, 0.f, 0.f};

    // ---- prologue: tile0 all 4 halves, tile1 A-halves  (12 ops/thread)
    stage_half(Ah0,      lda, lds8 + 0 * 8192, trow, tcol8, scol);
    stage_half(Ah1,      lda, lds8 + 1 * 8192, trow, tcol8, scol);
    stage_half(Bh0,      ldb, lds8 + 2 * 8192, trow, tcol8, scol);
    stage_half(Bh1,      ldb, lds8 + 3 * 8192, trow, tcol8, scol);
    stage_half(Ah0 + 64, lda, lds8 + 4 * 8192, trow, tcol8, scol);
    stage_half(Ah1 + 64, lda, lds8 + 5 * 8192, trow, tcol8, scol);
    asm volatile("s_waitcnt vmcnt(4)" ::: "memory");   // tile0's 8 ops done
    __builtin_amdgcn_s_barrier();

    for (int tt = 0; tt < NT; ++tt) {
        const int cur = tt & 1;
        const __bf16* LA = lds8 + (cur * 4 + wm) * 8192;
        const __bf16* LB = lds8 + (cur * 4 + 2 + (wn >> 1)) * 8192;
        __bf16* nxt = lds8 + ((1 - cur) * 4) * 8192;   // buffer of tile tt+1
        const bool stg = (tt + 1 < NT);
        const int  knx = (tt + 1) << 6;

#pragma unroll
        for (int p = 0; p < 4; ++p) {
            const int ar0 = (p >> 1) * 64;
            const int bb  = (wn & 1) * 64 + (p & 1) * 32;
            bf16x8 a0[4], a1[4], b0[2], b1[2];
#pragma unroll
            for (int i = 0; i < 4; ++i) {
                const int lr = ar0 + i * 16 + lane15;
                const int sw = (lr & 7) << 3;
                a0[i] = *(const bf16x8*)&LA[lr * 64 + ((lhi * 8) ^ sw)];
                a1[i] = *(const bf16x8*)&LA[lr * 64 + ((32 + lhi * 8) ^ sw)];
            }
#pragma unroll
            for (int j = 0; j < 2; ++j) {
                const int lr = bb + j * 16 + lane15;
                const int sw = (lr & 7) << 3;
                b0[j] = *(const bf16x8*)&LB[lr * 64 + ((lhi * 8) ^ sw)];
                b1[j] = *(const bf16x8*)&LB[lr * 64 + ((32 + lhi * 8) ^ sw)];
            }
            // stage tile tt+1's B-halves during phases 0/1 (A-halves were
            // issued at the previous boundary)
            if (p == 0 && stg) stage_half(Bh0 + knx, ldb, nxt + 2 * 8192, trow, tcol8, scol);
            if (p == 1 && stg) stage_half(Bh1 + knx, ldb, nxt + 3 * 8192, trow, tcol8, scol);

            __builtin_amdgcn_s_setprio(1);
#pragma unroll
            for (int i = 0; i < 4; ++i)
#pragma unroll
                for (int j = 0; j < 2; ++j) {
                    const int fi = (p >> 1) * 4 + i, fj = (p & 1) * 2 + j;
                    acc[fi][fj] = __builtin_amdgcn_mfma_f32_16x16x32_bf16(
                        a0[i], b0[j], acc[fi][fj], 0, 0, 0);
                    acc[fi][fj] = __builtin_amdgcn_mfma_f32_16x16x32_bf16(
                        a1[i], b1[j], acc[fi][fj], 0, 0, 0);
                }
            __builtin_amdgcn_s_setprio(0);
            __builtin_amdgcn_s_barrier();
        }

        // ---- boundary into tile tt+1
        if (tt + 1 < NT) {
            if (tt + 2 < NT) {
                // buf[cur] is free (phase-3 barrier): issue tile tt+2's A-halves
                const int k2 = (tt + 2) << 6;
                __bf16* nn = lds8 + (cur * 4) * 8192;
                stage_half(Ah0 + k2, lda, nn + 0 * 8192, trow, tcol8, scol);
                stage_half(Ah1 + k2, lda, nn + 1 * 8192, trow, tcol8, scol);
                asm volatile("s_waitcnt vmcnt(4)" ::: "memory");  // tile tt+1 ready
            } else {
                asm volatile("s_waitcnt vmcnt(0)" ::: "memory");  // final drain
            }
            __builtin_amdgcn_s_barrier();
        }
    }

    // ---- epilogue
    const int rbase = lhi * 4;
#pragma unroll
    for (int fi = 0; fi < 8; ++fi) {
#pragma unroll
        for (int fj = 0; fj < 4; ++fj) {
#pragma unroll
            for (int r = 0; r < 4; ++r) {
                const int m = m0 + wm * 128 + fi * 16 + rbase + r;
                const int n = n0 + wn * 64 + fj * 16 + lane15;
                const float v = acc[fi][fj][r];
                if constexpr (MODE == 0) {
                    if (m < DINNER) C0[(size_t)n * DINNER + m] = v;
                    else            C1b[(size_t)n * DINNER + (m - DINNER)] = f2bf(v);
                } else {
                    C0[(size_t)n * ldc + m] = v;
                }
            }
        }
    }
}

// ---------------------------------------------------------------------------
// m97-style 128x128 bf16 MFMA GEMM (small GEMMs: x_proj, dt_proj).
// MODE 2: softplus(v + bias[m]) -> C0[n*ldc+m] fp32          [dt_proj]
// MODE 3: m<128 -> C1b bf16 [n*128+m]; 128<=m<160 -> C0 fp32 [n*32+m-128]
// ---------------------------------------------------------------------------
template <int MODE>
__global__ __launch_bounds__(256)
void gemm_bf16(const __bf16* __restrict__ A, const __bf16* __restrict__ Bt,
               float* __restrict__ C0, __bf16* __restrict__ C1b,
               const float* __restrict__ bias,
               int Mvalid, int K, int lda, int ldb, int ldc)
{
    __shared__ __align__(16) __bf16 As[128 * 64];
    __shared__ __align__(16) __bf16 Bs[128 * 64];

    const int t  = threadIdx.x;
    const int m0 = blockIdx.y * 128;
    const int n0 = blockIdx.x * 128;
    const int l  = t & 63;
    const int w  = t >> 6;
    const int wr = (w >> 1) * 64;
    const int wc = (w & 1) * 64;
    const int lrow = t >> 3;
    const int lk   = (t & 7) * 8;

    f32x4 acc[4][4];
#pragma unroll
    for (int i = 0; i < 4; ++i)
#pragma unroll
        for (int j = 0; j < 4; ++j) acc[i][j] = (f32x4){0.f, 0.f, 0.f, 0.f};

    for (int k0 = 0; k0 < K; k0 += 64) {
#pragma unroll
        for (int q = 0; q < 4; ++q) {
            const int row = q * 32 + lrow;
            load_lds16(A  + (size_t)(m0 + row) * lda + k0 + lk, &As[row * 64 + lk]);
            load_lds16(Bt + (size_t)(n0 + row) * ldb + k0 + lk, &Bs[row * 64 + lk]);
        }
        __syncthreads();

#pragma unroll
        for (int kk = 0; kk < 2; ++kk) {
            const int krd = kk * 32 + (l >> 4) * 8;
            bf16x8 a[4], b[4];
#pragma unroll
            for (int i = 0; i < 4; ++i) {
                a[i] = *(const bf16x8*)&As[(wr + i * 16 + (l & 15)) * 64 + krd];
                b[i] = *(const bf16x8*)&Bs[(wc + i * 16 + (l & 15)) * 64 + krd];
            }
#pragma unroll
            for (int i = 0; i < 4; ++i)
#pragma unroll
                for (int j = 0; j < 4; ++j)
                    acc[i][j] = __builtin_amdgcn_mfma_f32_16x16x32_bf16(
                        a[i], b[j], acc[i][j], 0, 0, 0);
        }
        __syncthreads();
    }

    const int rbase = (l >> 4) * 4;
    const int cbase = l & 15;
#pragma unroll
    for (int i = 0; i < 4; ++i) {
#pragma unroll
        for (int j = 0; j < 4; ++j) {
#pragma unroll
            for (int r = 0; r < 4; ++r) {
                const int m = m0 + wr + i * 16 + rbase + r;
                const int n = n0 + wc + j * 16 + cbase;
                const float v = acc[i][j][r];
                if constexpr (MODE == 2) {
                    const float vb = v + bias[m];
                    const float sp = (vb > 20.f) ? vb : log1pf(__expf(vb));
                    C0[(size_t)n * ldc + m] = sp;
                } else {   // MODE 3
                    if (m < 128)      C1b[(size_t)n * 128 + m] = f2bf(v);
                    else if (m < 160) C0[(size_t)n * 32 + (m - 128)] = v;
                }
            }
        }
    }
}

// ---------------------------------------------------------------------------
__global__ __launch_bounds__(256)
void cvt_bf16(const float* __restrict__ in, __bf16* __restrict__ out, int n8)
{
    const int i = blockIdx.x * 256 + threadIdx.x;
    if (i >= n8) return;
    const size_t base = (size_t)i * 8;
    const float4 a = *(const float4*)&in[base];
    const float4 b = *(const float4*)&in[base + 4];
    __align__(16) __bf16 o[8];
    o[0] = f2bf(a.x); o[1] = f2bf(a.y); o[2] = f2bf(a.z); o[3] = f2bf(a.w);
    o[4] = f2bf(b.x); o[5] = f2bf(b.y); o[6] = f2bf(b.z); o[7] = f2bf(b.w);
    *(bf16x8*)&out[base] = *(const bf16x8*)o;
}

__global__ __launch_bounds__(256)
void cvt_xproj(const float* __restrict__ in, __bf16* __restrict__ out)
{
    const int i = blockIdx.x * 256 + threadIdx.x;
    const size_t base = (size_t)i * 8;
    const int row = (int)(base >> 12);
    __align__(16) __bf16 o[8];
    if (row < 160) {
        const float4 a = *(const float4*)&in[base];
        const float4 b = *(const float4*)&in[base + 4];
        o[0] = f2bf(a.x); o[1] = f2bf(a.y); o[2] = f2bf(a.z); o[3] = f2bf(a.w);
        o[4] = f2bf(b.x); o[5] = f2bf(b.y); o[6] = f2bf(b.z); o[7] = f2bf(b.w);
    } else {
#pragma unroll
        for (int k = 0; k < 8; ++k) o[k] = f2bf(0.f);
    }
    *(bf16x8*)&out[base] = *(const bf16x8*)o;
}

// ---------------------------------------------------------------------------
__global__ __launch_bounds__(256)
void conv_silu(const float* __restrict__ x, const float* __restrict__ conv_w,
               __bf16* __restrict__ xact_bf)
{
    const size_t idx = (size_t)blockIdx.x * 256 + threadIdx.x;
    const int e = (int)(idx & (DINNER - 1));
    const int n = (int)(idx >> 12);

    const float4 w = *(const float4*)&conv_w[e * 4];
    float s = w.w * x[idx];
    if (n >= 2) s += w.z * x[idx - (size_t)2 * DINNER];
    if (n >= 4) s += w.y * x[idx - (size_t)4 * DINNER];
    if (n >= 6) s += w.x * x[idx - (size_t)6 * DINNER];
    const float v = s / (1.f + __expf(-s));
    xact_bf[idx] = f2bf(v);
}

// ---------------------------------------------------------------------------
// Chunked selective scan.  B/C now come from compact xbc [NTOK][32] fp32.
// ---------------------------------------------------------------------------
__global__ __launch_bounds__(256)
void scan_partial(const float* __restrict__ delta, const __bf16* __restrict__ u,
                  const float* __restrict__ xbc, const float* __restrict__ A_log,
                  float2* __restrict__ PS)
{
    const int e     = blockIdx.x * 256 + threadIdx.x;
    const int chunk = blockIdx.y;
    const int b     = blockIdx.z;

    __shared__ float BC[CHUNK][32];
    for (int i = threadIdx.x; i < CHUNK * 32; i += 256) {
        const int ll = i >> 5, f = i & 31;
        BC[ll][f] = xbc[(size_t)((chunk * CHUNK + ll) * BATCH + b) * 32 + f];
    }

    float Av[16];
#pragma unroll
    for (int s = 0; s < 16; s += 4) {
        float4 tv = *(const float4*)&A_log[e * 16 + s];
        Av[s] = -__expf(tv.x); Av[s + 1] = -__expf(tv.y);
        Av[s + 2] = -__expf(tv.z); Av[s + 3] = -__expf(tv.w);
    }
    __syncthreads();

    float P[16], S[16];
#pragma unroll
    for (int s = 0; s < 16; ++s) { P[s] = 1.f; S[s] = 0.f; }

#pragma unroll 4
    for (int ll = 0; ll < CHUNK; ++ll) {
        const int tok = (chunk * CHUNK + ll) * BATCH + b;
        const size_t ce = (size_t)tok * DINNER + e;
        const float dl = delta[ce];
        const float du = dl * (float)u[ce];
#pragma unroll
        for (int s = 0; s < 16; ++s) {
            const float dA = __expf(dl * Av[s]);
            S[s] = fmaf(dA, S[s], du * BC[ll][s]);
            P[s] *= dA;
        }
    }

    float2* outp = PS + ((size_t)(chunk * BATCH + b) * DINNER + e) * 16;
#pragma unroll
    for (int s = 0; s < 16; ++s) outp[s] = make_float2(P[s], S[s]);
}

__global__ __launch_bounds__(256)
void scan_combine(const float2* __restrict__ PS, float* __restrict__ Hinit)
{
    const size_t pos = (size_t)blockIdx.x * 256 + threadIdx.x;
    const size_t stride = (size_t)BATCH * DINNER * 16;
    float h = 0.f;
#pragma unroll
    for (int c = 0; c < NCHUNK; ++c) {
        Hinit[c * stride + pos] = h;
        const float2 ps = PS[c * stride + pos];
        h = fmaf(ps.x, h, ps.y);
    }
}

__global__ __launch_bounds__(256)
void scan_final(const float* __restrict__ delta, const __bf16* __restrict__ u,
                const float* __restrict__ xbc, const float* __restrict__ Hinit,
                const __bf16* __restrict__ z_bf, __bf16* __restrict__ y_bf,
                const float* __restrict__ A_log, const float* __restrict__ Dvec)
{
    const int e     = blockIdx.x * 256 + threadIdx.x;
    const int chunk = blockIdx.y;
    const int b     = blockIdx.z;

    __shared__ float BC[CHUNK][32];
    for (int i = threadIdx.x; i < CHUNK * 32; i += 256) {
        const int ll = i >> 5, f = i & 31;
        BC[ll][f] = xbc[(size_t)((chunk * CHUNK + ll) * BATCH + b) * 32 + f];
    }

    float Av[16];
#pragma unroll
    for (int s = 0; s < 16; s += 4) {
        float4 tv = *(const float4*)&A_log[e * 16 + s];
        Av[s] = -__expf(tv.x); Av[s + 1] = -__expf(tv.y);
        Av[s + 2] = -__expf(tv.z); Av[s + 3] = -__expf(tv.w);
    }
    const float Dv = Dvec[e];

    float h[16];
    const float* hi = Hinit + (size_t)chunk * BATCH * DINNER * 16
                            + ((size_t)b * DINNER + e) * 16;
#pragma unroll
    for (int s = 0; s < 16; s += 4) *(float4*)&h[s] = *(const float4*)&hi[s];
    __syncthreads();

#pragma unroll 2
    for (int ll = 0; ll < CHUNK; ++ll) {
        const int tok = (chunk * CHUNK + ll) * BATCH + b;
        const size_t ce = (size_t)tok * DINNER + e;
        const float dl = delta[ce];
        const float ul = (float)u[ce];
        const float du = dl * ul;
        float y = 0.f;
#pragma unroll
        for (int s = 0; s < 16; ++s) {
            const float dA = __expf(dl * Av[s]);
            h[s] = fmaf(dA, h[s], du * BC[ll][s]);
            y = fmaf(h[s], BC[ll][16 + s], y);
        }
        const float zl = (float)z_bf[ce];
        const float sig = 1.f / (1.f + __expf(-zl));
        y_bf[ce] = f2bf((y + ul * Dv) * (zl * sig));
    }
}

// ---------------------------------------------------------------------------
extern "C" void kernel_launch(void* const* d_in, const int* in_sizes, int n_in,
                              void* d_out, int out_size, void* d_ws, size_t ws_size,
                              hipStream_t stream)
{
    const float* hidden    = (const float*)d_in[0];
    const float* in_proj_w = (const float*)d_in[1];
    const float* conv_w    = (const float*)d_in[2];
    const float* x_proj_w  = (const float*)d_in[3];
    const float* dt_proj_w = (const float*)d_in[4];
    const float* dt_proj_b = (const float*)d_in[5];
    const float* A_log     = (const float*)d_in[6];
    const float* Dvec      = (const float*)d_in[7];
    const float* out_proj_w= (const float*)d_in[8];
    float* out = (float*)d_out;

    // -------- workspace (239,599,616 B — identical total to R4's passing run)
    char* p = (char*)d_ws;
    const size_t NBIG = (size_t)NTOK * DINNER;
    float*  xbuf    = (float*)p;    p += NBIG * 4;                        // x -> delta
    __bf16* z_bf    = (__bf16*)p;   p += NBIG * 2;                        // z
    __bf16* xact_bf = (__bf16*)p;   p += NBIG * 2;                        // u
    __bf16* dtr_bf  = (__bf16*)p;   p += (size_t)NTOK * 128 * 2;         // dt_r (bf16)
    float*  xbc     = (float*)p;    p += (size_t)NTOK * 32 * 4;          // B|C (fp32)
    __bf16* w_xp_bf = (__bf16*)p;   p += (size_t)256 * DINNER * 2;
    __bf16* w_out_bf= (__bf16*)p;   p += (size_t)DMODEL * DINNER * 2;
    char*   G       = p;            p += (size_t)2 * DINNER * DMODEL * 2; // w_in_bf / PS+Hinit
    __bf16* hid_bf  = (__bf16*)p;   p += (size_t)NTOK * DMODEL * 2;
    __bf16* y_bf    = (__bf16*)p;   p += NBIG * 2;
    __bf16* dtw_bf  = (__bf16*)p;   p += (size_t)DINNER * DTRANK * 2;
    const size_t required = (size_t)(p - (char*)d_ws);
    if (ws_size < required) return;

    __bf16* w_in_bf = (__bf16*)G;
    float2* PS      = (float2*)G;                                         // 16.8 MB
    float*  Hinit   = (float*)(G + (size_t)NCHUNK * BATCH * DINNER * 16 * 8);

    // 0) conversions
    cvt_bf16<<<(int)(NTOK * DMODEL / 2048), 256, 0, stream>>>(hidden, hid_bf, NTOK * DMODEL / 8);
    cvt_bf16<<<(int)(2 * DINNER * DMODEL / 2048), 256, 0, stream>>>(in_proj_w, w_in_bf, 2 * DINNER * DMODEL / 8);
    cvt_bf16<<<(int)(DMODEL * DINNER / 2048), 256, 0, stream>>>(out_proj_w, w_out_bf, DMODEL * DINNER / 8);
    cvt_bf16<<<(int)(DINNER * DTRANK / 2048), 256, 0, stream>>>(dt_proj_w, dtw_bf, DINNER * DTRANK / 8);
    cvt_xproj<<<(int)(256 * DINNER / 2048), 256, 0, stream>>>(x_proj_w, w_xp_bf);

    // 1) in_proj (256^2 8-phase): x (fp32) | z (bf16).  grid 32*16=512 (%8==0)
    gemm8<0><<<(2 * DINNER / 256) * (NTOK / 256), 512, 0, stream>>>(
        w_in_bf, hid_bf, xbuf, z_bf, DMODEL, DMODEL, DMODEL, DINNER, NTOK / 256);

    // 2) conv + silu -> u (bf16)
    conv_silu<<<(int)(NBIG / 256), 256, 0, stream>>>(xbuf, conv_w, xact_bf);

    // 3) x_proj (128^2): dt_r -> bf16, B|C -> fp32 compact
    gemm_bf16<3><<<dim3(NTOK / 128, 2), 256, 0, stream>>>(
        w_xp_bf, xact_bf, xbc, dtr_bf, nullptr, 160, DINNER, DINNER, DINNER, 0);

    // 4) dt_proj (128^2, K=128) + softplus -> delta (over xbuf)
    gemm_bf16<2><<<dim3(NTOK / 128, DINNER / 128), 256, 0, stream>>>(
        dtw_bf, dtr_bf, xbuf, nullptr, dt_proj_b, DINNER, DTRANK, DTRANK, DTRANK, DINNER);

    // 5) chunked scan (PS/Hinit overwrite w_in_bf — dead after step 1)
    scan_partial<<<dim3(DINNER / 256, NCHUNK, BATCH), 256, 0, stream>>>(
        xbuf, xact_bf, xbc, A_log, PS);
    scan_combine<<<(BATCH * DINNER * 16) / 256, 256, 0, stream>>>(PS, Hinit);
    scan_final<<<dim3(DINNER / 256, NCHUNK, BATCH), 256, 0, stream>>>(
        xbuf, xact_bf, xbc, Hinit, z_bf, y_bf, A_log, Dvec);

    // 6) out_proj (256^2 8-phase).  grid 8*16=128 (%8==0)
    gemm8<1><<<(DMODEL / 256) * (NTOK / 256), 512, 0, stream>>>(
        w_out_bf, y_bf, out, nullptr, DINNER, DINNER, DINNER, DMODEL, NTOK / 256);
}